// Round 10
// baseline (520.184 us; speedup 1.0000x reference)
//
#include <hip/hip_runtime.h>
#include <math.h>

#define IMG   512
#define NFILT 32
#define PI_F  3.14159265358979323846f
#define GS    104      // LDS row stride in halves (208 B): b128 across lanes = 2-way banks (free)

typedef _Float16 v8h __attribute__((ext_vector_type(8)));
typedef float    v4f __attribute__((ext_vector_type(4)));

__device__ __forceinline__ unsigned pkrtz(float a, float b) {
    typedef __fp16 f16x2 __attribute__((ext_vector_type(2)));
    union { f16x2 h; unsigned u; } x;
    x.h = __builtin_amdgcn_cvt_pkrtz(a, b);
    return x.u;
}

template <int CTRL>
__device__ __forceinline__ float dpp_add(float v) {
    int t = __builtin_amdgcn_update_dpp(0, __float_as_int(v), CTRL, 0xf, 0xf, true);
    return v + __int_as_float(t);
}

#if __has_builtin(__builtin_amdgcn_sqrtf)
__device__ __forceinline__ float fsqrt(float x) { return __builtin_amdgcn_sqrtf(x); }
#else
__device__ __forceinline__ float fsqrt(float x) { return sqrtf(x); }
#endif

// ---------------------------------------------------------------------------
// tabs layout (dwords): [filter:32][table:5][copy:8][block:20][dw:4]
//   tables: 0 g_re, 1 g_im, 2 f_re, 3 f_im, 4 -f_im
//   copy c, block i holds halves tap(8*i-64+c .. +7); tap(t)=0 unless 0<=t<32.
// One block per filter: compute 160 base taps into LDS once, expand by gather.
// ---------------------------------------------------------------------------
__global__ void make_tables(unsigned* __restrict__ tabs) {
    __shared__ _Float16 P[5][168];      // P[tbl][p] = tap(p-64), zero-padded
    const int fo = blockIdx.x;
    const int tid = threadIdx.x;
    for (int e = tid; e < 5 * 168; e += 256) ((_Float16*)P)[e] = (_Float16)0.0f;
    __syncthreads();
    if (tid < 160) {
        int tbl = tid >> 5, t = tid & 31;
        int s = (fo >> 3) + 1, o = fo & 7;
        float theta = (float)o * (PI_F / 7.0f);      // linspace(0, pi, 8)
        float sf = (float)s * 2.0f;                  // scale * SIGMA
        float kf = 2.0f * PI_F / ((float)s * sf);
        float a = kf * cosf(theta), b = kf * sinf(theta);
        float d = (float)(t - 16);
        float env = expf(-0.5f * d * d / (sf * sf));
        float v;
        switch (tbl) {
            case 0: v =  env * cosf(b * d); break;
            case 1: v =  env * sinf(b * d); break;
            case 2: v =  env * cosf(a * d); break;
            case 3: v =  env * sinf(a * d); break;
            default: v = -env * sinf(a * d); break;
        }
        P[tbl][t + 64] = (_Float16)v;
    }
    __syncthreads();
    unsigned* dst = tabs + (size_t)fo * 3200;
    for (int e = tid; e < 3200; e += 256) {
        int tbl  = e / 640;  int rem2 = e - tbl * 640;
        int copy = rem2 / 80; int idw = rem2 - copy * 80;
        int p0 = (idw >> 2) * 8 + copy + (idw & 3) * 2;   // = t0 + 64
        union { unsigned u; _Float16 h[2]; } p;
        p.h[0] = P[tbl][p0];
        p.h[1] = P[tbl][p0 + 1];
        dst[e] = p.u;
    }
}

__device__ __forceinline__ v8h ldfrag(const uint4* p) {
    union { uint4 u; v8h h; } x; x.u = *p; return x.h;
}

// ---------------------------------------------------------------------------
// Fused kernel: S0 pool + MFMA separable Gabor conv + |.| + pool -> S1.
// 1536 blocks = (n:8)(tile:64)(fsplit:3), 512 threads, ~11 filters per block.
// LDS 46.6 KB -> 3 blocks/CU; latency-bound -> cross-filter fragment prefetch
// (double-buffered register sets, ~2000-cycle load->use distance).
// ---------------------------------------------------------------------------
__launch_bounds__(512, 6)
__global__ void conv_kernel(const float* __restrict__ x,
                            const uint4* __restrict__ tabs,
                            float* __restrict__ s0out,
                            float* __restrict__ s1out) {
    __shared__ _Float16 gray[96 * GS];   // 19968 B
    __shared__ _Float16 Tre [64 * GS];   // 13312 B  (T^T: [col c][row m])
    __shared__ _Float16 Tim [64 * GS];   // 13312 B

    const int bx = blockIdx.x;
    const int n  = bx / 192;
    const int rem = bx - n * 192;
    const int t6 = rem / 3;
    const int fs = rem - t6 * 3;
    const int f0 = (fs * NFILT) / 3;          // 0, 10, 21
    const int f1 = ((fs + 1) * NFILT) / 3;    // 10, 21, 32
    const int ty = t6 >> 3, tx = t6 & 7;
    const int r0g = ty * 64 - 16;
    const int c0g = tx * 64 - 16;
    const int tid = threadIdx.x;

    // ---- stage gray = 3-channel mean (f16), zero outside image & in pads ----
    const float* xb = x + (size_t)n * 3 * IMG * IMG;
    for (int e = tid; e < 96 * GS; e += 512) {
        int hr = e / GS, hc = e - hr * GS;
        int gr = r0g + hr, gc = c0g + hc;
        float v = 0.0f;
        if (hr < 95 && hc < 95 && (unsigned)gr < IMG && (unsigned)gc < IMG) {
            size_t off = (size_t)gr * IMG + gc;
            v = (xb[off] + xb[off + IMG * IMG] + xb[off + 2 * IMG * IMG]) * (1.0f / 3.0f);
        }
        gray[e] = (_Float16)v;
    }
    __syncthreads();

    // ---- fused S0 (only fsplit 0): 16x16 avg-pool of gray interior ----
    if (fs == 0 && tid < 256) {
        int cell = tid >> 4, sub = tid & 15;
        int pr = cell >> 2, pc = cell & 3;
        const _Float16* row = &gray[(16 + pr * 16 + sub) * GS + 16 + pc * 16];
        float s = 0.0f;
        #pragma unroll
        for (int j = 0; j < 16; ++j) s += (float)row[j];
        s += __shfl_xor(s, 1);
        s += __shfl_xor(s, 2);
        s += __shfl_xor(s, 4);
        s += __shfl_xor(s, 8);
        if (sub == 0)
            s0out[(size_t)n * 1024 + (ty * 4 + pr) * 32 + (tx * 4 + pc)] = s * (1.0f / 256.0f);
    }

    const int lane = tid & 63;
    const int w    = tid >> 6;
    const int r4   = w & 3;                 // pass A N-tile / pass B M-tile
    const int half = w >> 2;                // splits mt (pass A) / nt (pass B)
    const int nn   = lane & 15;
    const int q8   = (lane >> 4) << 3;      // k-offset within K=32 fragment
    const int q4   = (lane >> 4) << 2;      // C/D row base within 16-tile
    const int cr   = r4 * 16 + nn;          // pass A: col c; pass B: row r
    const int u    = q8 - cr + 64;          // tap-phase for fragment tables
    const int b0   = r4 >> 1;               // first needed k-block (band skip)
    const int uoff = (u & 7) * 20 + (u >> 3);
    float* s1b = s1out + (size_t)n * NFILT * 32 * 32;

    // ---- hoist filter-invariant gray A-fragments into registers ----
    v8h Agray[3][2];
    #pragma unroll
    for (int mi = 0; mi < 3; ++mi)
        #pragma unroll
        for (int j = 0; j < 2; ++j)
            Agray[mi][j] = *(const v8h*)(&gray[((half * 3 + mi) * 16 + nn) * GS + (b0 + j) * 32 + q8]);

    v8h GreA[2], GimA[2], FreA[2], FimA[2], FiNA[2];
    v8h GreB[2], GimB[2], FreB[2], FimB[2], FiNB[2];

#define PREF(SET, F)                                                          \
    {                                                                         \
        const uint4* fb_ = tabs + (size_t)(F) * 800 + uoff;                   \
        _Pragma("unroll")                                                     \
        for (int j = 0; j < 2; ++j) {                                         \
            int idx = (b0 + j) * 4;                                           \
            Gre##SET[j] = ldfrag(fb_ + idx);                                  \
            Gim##SET[j] = ldfrag(fb_ + 160 + idx);                            \
            Fre##SET[j] = ldfrag(fb_ + 320 + idx);                            \
            Fim##SET[j] = ldfrag(fb_ + 480 + idx);                            \
            FiN##SET[j] = ldfrag(fb_ + 640 + idx);                            \
        }                                                                     \
    }

#define STEP(CUR, NXT, F, DOPF)                                               \
    {                                                                         \
        if (DOPF) PREF(NXT, (F) + 1);                                         \
        /* pass A: T = gray . G (A-operand from registers) */                 \
        _Pragma("unroll")                                                     \
        for (int mi = 0; mi < 3; ++mi) {                                      \
            int mt = half * 3 + mi;                                           \
            v4f aR = {0.f, 0.f, 0.f, 0.f}, aI = {0.f, 0.f, 0.f, 0.f};         \
            _Pragma("unroll")                                                 \
            for (int j = 0; j < 2; ++j) {                                     \
                aR = __builtin_amdgcn_mfma_f32_16x16x32_f16(Agray[mi][j], Gre##CUR[j], aR, 0, 0, 0); \
                aI = __builtin_amdgcn_mfma_f32_16x16x32_f16(Agray[mi][j], Gim##CUR[j], aI, 0, 0, 0); \
            }                                                                 \
            int mb = mt * 16 + q4;                                            \
            uint2 pr, pi;                                                     \
            pr.x = pkrtz(aR[0], aR[1]);  pr.y = pkrtz(aR[2], aR[3]);          \
            pi.x = pkrtz(aI[0], aI[1]);  pi.y = pkrtz(aI[2], aI[3]);          \
            *(uint2*)(&Tre[cr * GS + mb]) = pr;                               \
            *(uint2*)(&Tim[cr * GS + mb]) = pi;                               \
        }                                                                     \
        __syncthreads();                                                      \
        /* pass B: Out = F . T */                                             \
        _Pragma("unroll")                                                     \
        for (int ni = 0; ni < 2; ++ni) {                                      \
            int nt = half * 2 + ni;                                           \
            v4f cR = {0.f, 0.f, 0.f, 0.f}, cI = {0.f, 0.f, 0.f, 0.f};         \
            _Pragma("unroll")                                                 \
            for (int j = 0; j < 2; ++j) {                                     \
                v8h tR = *(const v8h*)(&Tre[(nt * 16 + nn) * GS + (b0 + j) * 32 + q8]); \
                v8h tI = *(const v8h*)(&Tim[(nt * 16 + nn) * GS + (b0 + j) * 32 + q8]); \
                cR = __builtin_amdgcn_mfma_f32_16x16x32_f16(Fre##CUR[j], tR, cR, 0, 0, 0); \
                cR = __builtin_amdgcn_mfma_f32_16x16x32_f16(FiN##CUR[j], tI, cR, 0, 0, 0); \
                cI = __builtin_amdgcn_mfma_f32_16x16x32_f16(Fre##CUR[j], tI, cI, 0, 0, 0); \
                cI = __builtin_amdgcn_mfma_f32_16x16x32_f16(Fim##CUR[j], tR, cI, 0, 0, 0); \
            }                                                                 \
            float m = 0.0f;                                                   \
            _Pragma("unroll")                                                 \
            for (int r = 0; r < 4; ++r)                                       \
                m += fsqrt(fmaf(cR[r], cR[r], fmaf(cI[r], cI[r], 1e-8f)));    \
            m = dpp_add<0xB1>(m);   /* quad_perm xor1 */                      \
            m = dpp_add<0x4E>(m);   /* quad_perm xor2 */                      \
            m = dpp_add<0x141>(m);  /* row_half_mirror */                     \
            m = dpp_add<0x140>(m);  /* row_mirror */                          \
            m += __shfl_xor(m, 16);                                           \
            m += __shfl_xor(m, 32);                                           \
            if (lane == 0)                                                    \
                s1b[((size_t)(F) * 32 + (ty * 4 + r4)) * 32 + (tx * 4 + nt)] = m * (1.0f / 256.0f); \
        }                                                                     \
        __syncthreads();                                                      \
    }

    PREF(A, f0);
    int fo = f0;
    while (fo + 2 <= f1) {
        STEP(A, B, fo, true);
        STEP(B, A, fo + 1, (fo + 2 < f1));
        fo += 2;
    }
    if (fo < f1) STEP(A, B, fo, false);
#undef STEP
#undef PREF
}

// ---------------------------------------------------------------------------
extern "C" void kernel_launch(void* const* d_in, const int* in_sizes, int n_in,
                              void* d_out, int out_size, void* d_ws, size_t ws_size,
                              hipStream_t stream) {
    const float* x = (const float*)d_in[0];
    float* out = (float*)d_out;
    unsigned* tabs = (unsigned*)d_ws;          // 102400 dwords = 400 KB scratch

    hipLaunchKernelGGL(make_tables, dim3(32), dim3(256), 0, stream, tabs);
    hipLaunchKernelGGL(conv_kernel, dim3(1536), dim3(512), 0, stream,
                       x, (const uint4*)tabs, out, out + 8192);
}

// Round 11
// 182.102 us; speedup vs baseline: 2.8565x; 2.8565x over previous
//
#include <hip/hip_runtime.h>
#include <math.h>

#define IMG   512
#define NFILT 32
#define PI_F  3.14159265358979323846f
#define GS    104      // LDS row stride in halves (208 B): b128 across lanes = 2-way banks (free)

typedef _Float16 v8h __attribute__((ext_vector_type(8)));
typedef float    v4f __attribute__((ext_vector_type(4)));

__device__ __forceinline__ unsigned pkrtz(float a, float b) {
    typedef __fp16 f16x2 __attribute__((ext_vector_type(2)));
    union { f16x2 h; unsigned u; } x;
    x.h = __builtin_amdgcn_cvt_pkrtz(a, b);
    return x.u;
}

template <int CTRL>
__device__ __forceinline__ float dpp_add(float v) {
    int t = __builtin_amdgcn_update_dpp(0, __float_as_int(v), CTRL, 0xf, 0xf, true);
    return v + __int_as_float(t);
}

#if __has_builtin(__builtin_amdgcn_sqrtf)
__device__ __forceinline__ float fsqrt(float x) { return __builtin_amdgcn_sqrtf(x); }
#else
__device__ __forceinline__ float fsqrt(float x) { return sqrtf(x); }
#endif

__device__ __forceinline__ v8h ldfrag(const uint4* p) {
    union { uint4 u; v8h h; } x; x.u = *p; return x.h;
}

__device__ __forceinline__ v8h neg8h(v8h a) {           // flip f16 sign bits
    union { v8h h; uint4 u; } x; x.h = a;
    x.u.x ^= 0x80008000u; x.u.y ^= 0x80008000u;
    x.u.z ^= 0x80008000u; x.u.w ^= 0x80008000u;
    return x.h;
}

// ---------------------------------------------------------------------------
// tabs layout (dwords): [filter:32][table:5][copy:8][block:20][dw:4]
//   tables: 0 g_re, 1 g_im, 2 f_re, 3 f_im, 4 -f_im (tbl4 kept for layout)
//   copy c, block i holds halves tap(8*i-64+c .. +7); tap(t)=0 unless 0<=t<32.
// One block per filter: compute 160 base taps into LDS once, expand by gather.
// ---------------------------------------------------------------------------
__global__ void make_tables(unsigned* __restrict__ tabs) {
    __shared__ _Float16 P[5][168];      // P[tbl][p] = tap(p-64), zero-padded
    const int fo = blockIdx.x;
    const int tid = threadIdx.x;
    for (int e = tid; e < 5 * 168; e += 256) ((_Float16*)P)[e] = (_Float16)0.0f;
    __syncthreads();
    if (tid < 160) {
        int tbl = tid >> 5, t = tid & 31;
        int s = (fo >> 3) + 1, o = fo & 7;
        float theta = (float)o * (PI_F / 7.0f);      // linspace(0, pi, 8)
        float sf = (float)s * 2.0f;                  // scale * SIGMA
        float kf = 2.0f * PI_F / ((float)s * sf);
        float a = kf * cosf(theta), b = kf * sinf(theta);
        float d = (float)(t - 16);
        float env = expf(-0.5f * d * d / (sf * sf));
        float v;
        switch (tbl) {
            case 0: v =  env * cosf(b * d); break;
            case 1: v =  env * sinf(b * d); break;
            case 2: v =  env * cosf(a * d); break;
            case 3: v =  env * sinf(a * d); break;
            default: v = -env * sinf(a * d); break;
        }
        P[tbl][t + 64] = (_Float16)v;
    }
    __syncthreads();
    unsigned* dst = tabs + (size_t)fo * 3200;
    for (int e = tid; e < 3200; e += 256) {
        int tbl  = e / 640;  int rem2 = e - tbl * 640;
        int copy = rem2 / 80; int idw = rem2 - copy * 80;
        int p0 = (idw >> 2) * 8 + copy + (idw & 3) * 2;   // = t0 + 64
        union { unsigned u; _Float16 h[2]; } p;
        p.h[0] = P[tbl][p0];
        p.h[1] = P[tbl][p0 + 1];
        dst[e] = p.u;
    }
}

// ---------------------------------------------------------------------------
// Fused kernel: S0 pool + MFMA separable Gabor conv + |.| + pool -> S1.
// 1536 blocks = (n:8)(tile:64)(fsplit:3), 512 threads, ~11 filters per block.
// LDS 47.3 KB -> 3 blocks/CU.  Loop is vmem-drain-free after barrier 1:
// pooled S1 results staged in LDS, flushed once in an epilogue.
// ---------------------------------------------------------------------------
__launch_bounds__(512, 6)
__global__ void conv_kernel(const float* __restrict__ x,
                            const uint4* __restrict__ tabs,
                            float* __restrict__ s0out,
                            float* __restrict__ s1out) {
    __shared__ _Float16 gray[96 * GS];   // 19968 B
    __shared__ _Float16 Tre [64 * GS];   // 13312 B  (T^T: [col c][row m])
    __shared__ _Float16 Tim [64 * GS];   // 13312 B
    __shared__ float    s1st[11 * 16];   // 704 B, staged pooled outputs

    const int bx = blockIdx.x;
    const int n  = bx / 192;
    const int rem = bx - n * 192;
    const int t6 = rem / 3;
    const int fs = rem - t6 * 3;
    const int f0 = (fs * NFILT) / 3;          // 0, 10, 21
    const int f1 = ((fs + 1) * NFILT) / 3;    // 10, 21, 32
    const int ty = t6 >> 3, tx = t6 & 7;
    const int r0g = ty * 64 - 16;
    const int c0g = tx * 64 - 16;
    const int tid = threadIdx.x;

    // ---- stage gray = 3-channel mean (f16), zero outside image & in pads ----
    const float* xb = x + (size_t)n * 3 * IMG * IMG;
    for (int e = tid; e < 96 * GS; e += 512) {
        int hr = e / GS, hc = e - hr * GS;
        int gr = r0g + hr, gc = c0g + hc;
        float v = 0.0f;
        if (hr < 95 && hc < 95 && (unsigned)gr < IMG && (unsigned)gc < IMG) {
            size_t off = (size_t)gr * IMG + gc;
            v = (xb[off] + xb[off + IMG * IMG] + xb[off + 2 * IMG * IMG]) * (1.0f / 3.0f);
        }
        gray[e] = (_Float16)v;
    }
    __syncthreads();

    // ---- fused S0 (only fsplit 0): 16x16 avg-pool of gray interior ----
    if (fs == 0 && tid < 256) {
        int cell = tid >> 4, sub = tid & 15;
        int pr = cell >> 2, pc = cell & 3;
        const _Float16* row = &gray[(16 + pr * 16 + sub) * GS + 16 + pc * 16];
        float s = 0.0f;
        #pragma unroll
        for (int j = 0; j < 16; ++j) s += (float)row[j];
        s += __shfl_xor(s, 1);
        s += __shfl_xor(s, 2);
        s += __shfl_xor(s, 4);
        s += __shfl_xor(s, 8);
        if (sub == 0)
            s0out[(size_t)n * 1024 + (ty * 4 + pr) * 32 + (tx * 4 + pc)] = s * (1.0f / 256.0f);
    }

    const int lane = tid & 63;
    const int w    = tid >> 6;
    const int r4   = w & 3;                 // pass A N-tile / pass B M-tile
    const int half = w >> 2;                // splits mt (pass A) / nt (pass B)
    const int nn   = lane & 15;
    const int q8   = (lane >> 4) << 3;      // k-offset within K=32 fragment
    const int q4   = (lane >> 4) << 2;      // C/D row base within 16-tile
    const int cr   = r4 * 16 + nn;          // pass A: col c; pass B: row r
    const int u    = q8 - cr + 64;          // tap-phase for fragment tables
    const int b0   = r4 >> 1;               // first needed k-block (band skip)
    const int uoff = (u & 7) * 20 + (u >> 3);

    // ---- hoist filter-invariant gray A-fragments into registers ----
    v8h Agray[3][2];
    #pragma unroll
    for (int mi = 0; mi < 3; ++mi)
        #pragma unroll
        for (int j = 0; j < 2; ++j)
            Agray[mi][j] = *(const v8h*)(&gray[((half * 3 + mi) * 16 + nn) * GS + (b0 + j) * 32 + q8]);

    for (int fo = f0; fo < f1; ++fo) {
        const uint4* fb = tabs + (size_t)fo * 800 + uoff;

        // ---- phase 1: G fragments ----
        v8h Gre[2], Gim[2];
        #pragma unroll
        for (int j = 0; j < 2; ++j) {
            int idx = (b0 + j) * 4;
            Gre[j] = ldfrag(fb + idx);
            Gim[j] = ldfrag(fb + 160 + idx);
        }

        // ---- pass A: T = gray . G  (A-operand from registers) ----
        #pragma unroll
        for (int mi = 0; mi < 3; ++mi) {
            int mt = half * 3 + mi;
            v4f aR = {0.f, 0.f, 0.f, 0.f}, aI = {0.f, 0.f, 0.f, 0.f};
            #pragma unroll
            for (int j = 0; j < 2; ++j) {
                aR = __builtin_amdgcn_mfma_f32_16x16x32_f16(Agray[mi][j], Gre[j], aR, 0, 0, 0);
                aI = __builtin_amdgcn_mfma_f32_16x16x32_f16(Agray[mi][j], Gim[j], aI, 0, 0, 0);
            }
            // C/D: col=lane&15 -> c=cr, row=q4+reg -> m; write T^T[c][m] 4 halves
            int mb = mt * 16 + q4;
            uint2 pr, pi;
            pr.x = pkrtz(aR[0], aR[1]);  pr.y = pkrtz(aR[2], aR[3]);
            pi.x = pkrtz(aI[0], aI[1]);  pi.y = pkrtz(aI[2], aI[3]);
            *(uint2*)(&Tre[cr * GS + mb]) = pr;
            *(uint2*)(&Tim[cr * GS + mb]) = pi;
        }

        // ---- phase 2: F fragments (latency spans pass-A tail + barrier) ----
        v8h Fre[2], Fim[2];
        #pragma unroll
        for (int j = 0; j < 2; ++j) {
            int idx = (b0 + j) * 4;
            Fre[j] = ldfrag(fb + 320 + idx);
            Fim[j] = ldfrag(fb + 480 + idx);
        }
        __syncthreads();
        v8h FiN[2];
        FiN[0] = neg8h(Fim[0]);
        FiN[1] = neg8h(Fim[1]);

        // ---- pass B: Out = F . T  (wave: M-tile r4, nt in half's range) ----
        #pragma unroll
        for (int ni = 0; ni < 2; ++ni) {
            int nt = half * 2 + ni;
            v4f cR = {0.f, 0.f, 0.f, 0.f}, cI = {0.f, 0.f, 0.f, 0.f};
            #pragma unroll
            for (int j = 0; j < 2; ++j) {
                v8h tR = *(const v8h*)(&Tre[(nt * 16 + nn) * GS + (b0 + j) * 32 + q8]);
                v8h tI = *(const v8h*)(&Tim[(nt * 16 + nn) * GS + (b0 + j) * 32 + q8]);
                cR = __builtin_amdgcn_mfma_f32_16x16x32_f16(Fre[j], tR, cR, 0, 0, 0);
                cR = __builtin_amdgcn_mfma_f32_16x16x32_f16(FiN[j], tI, cR, 0, 0, 0);
                cI = __builtin_amdgcn_mfma_f32_16x16x32_f16(Fre[j], tI, cI, 0, 0, 0);
                cI = __builtin_amdgcn_mfma_f32_16x16x32_f16(Fim[j], tR, cI, 0, 0, 0);
            }
            // magnitude + full 16x16-cell pool (cell = (r4, nt)); stage in LDS
            float m = 0.0f;
            #pragma unroll
            for (int r = 0; r < 4; ++r)
                m += fsqrt(fmaf(cR[r], cR[r], fmaf(cI[r], cI[r], 1e-8f)));
            m = dpp_add<0xB1>(m);   // quad_perm xor1
            m = dpp_add<0x4E>(m);   // quad_perm xor2
            m = dpp_add<0x141>(m);  // row_half_mirror
            m = dpp_add<0x140>(m);  // row_mirror
            m += __shfl_xor(m, 16);
            m += __shfl_xor(m, 32);
            if (lane == 0)
                s1st[(fo - f0) * 16 + r4 * 4 + nt] = m;
        }
        __syncthreads();                    // T overwritten next filter
    }

    // ---- epilogue: flush staged S1 (loop ended with a barrier) ----
    float* s1b = s1out + (size_t)n * NFILT * 32 * 32;
    const int nf = f1 - f0;
    for (int e = tid; e < nf * 16; e += 512) {
        int fi = e >> 4, cell = e & 15;
        int r4c = cell >> 2, ntc = cell & 3;
        s1b[((size_t)(f0 + fi) * 32 + (ty * 4 + r4c)) * 32 + (tx * 4 + ntc)] =
            s1st[e] * (1.0f / 256.0f);
    }
}

// ---------------------------------------------------------------------------
extern "C" void kernel_launch(void* const* d_in, const int* in_sizes, int n_in,
                              void* d_out, int out_size, void* d_ws, size_t ws_size,
                              hipStream_t stream) {
    const float* x = (const float*)d_in[0];
    float* out = (float*)d_out;
    unsigned* tabs = (unsigned*)d_ws;          // 102400 dwords = 400 KB scratch

    hipLaunchKernelGGL(make_tables, dim3(32), dim3(256), 0, stream, tabs);
    hipLaunchKernelGGL(conv_kernel, dim3(1536), dim3(512), 0, stream,
                       x, (const uint4*)tabs, out, out + 8192);
}